// Round 2
// baseline (282.332 us; speedup 1.0000x reference)
//
#include <hip/hip_runtime.h>
#include <hip/hip_bf16.h>
#include <math.h>

typedef unsigned long long u64;
typedef unsigned char u8;
typedef unsigned short u16;
typedef unsigned int u32;

#define BB 8
#define CC 19
#define HH 512
#define WW 512
#define HWSZ (HH*WW)
#define NIMG 16

// ---------------------------------------------------------------------------
// 1) argmax over channel dim -> img_p = (cls*255)%256 = (u8)(-cls)
// ---------------------------------------------------------------------------
__global__ __launch_bounds__(256) void k_argmax(const float* __restrict__ pred,
                                                u8* __restrict__ img) {
    int idx = blockIdx.x * 256 + threadIdx.x;   // 4 pixels per thread
    int p4 = idx * 4;
    int b = p4 / HWSZ;
    int rem = p4 - b * HWSZ;
    const float4* base = (const float4*)(pred + (size_t)b * CC * HWSZ + rem);
    float4 best = base[0];
    int ix = 0, iy = 0, iz = 0, iw = 0;
    for (int c = 1; c < CC; ++c) {
        float4 v = base[(size_t)c * (HWSZ / 4)];
        if (v.x > best.x) { best.x = v.x; ix = c; }
        if (v.y > best.y) { best.y = v.y; iy = c; }
        if (v.z > best.z) { best.z = v.z; iz = c; }
        if (v.w > best.w) { best.w = v.w; iw = c; }
    }
    uchar4 o;
    o.x = (u8)(-ix); o.y = (u8)(-iy); o.z = (u8)(-iz); o.w = (u8)(-iw);
    *(uchar4*)(img + p4) = o;
}

// ---------------------------------------------------------------------------
// 2) img_l = floor(labels*255), labels in [0,1)
// ---------------------------------------------------------------------------
__global__ __launch_bounds__(256) void k_imgl(const float* __restrict__ lab,
                                              u8* __restrict__ img) {
    int idx = blockIdx.x * 256 + threadIdx.x;
    int p4 = idx * 4;
    float4 v = *(const float4*)(lab + p4);
    uchar4 o;
    o.x = (u8)(v.x * 255.0f);
    o.y = (u8)(v.y * 255.0f);
    o.z = (u8)(v.z * 255.0f);
    o.w = (u8)(v.w * 255.0f);
    *(uchar4*)(img + p4) = o;
}

// ---------------------------------------------------------------------------
// 3) Sobel (edge-replicate pad) + L1 mag + quantized direction.
//    magdir = mag (12 bits, <=2040) | dir<<12, dir in {0:0deg,1:45,2:90,3:135}
// ---------------------------------------------------------------------------
__global__ __launch_bounds__(256) void k_grad(const u8* __restrict__ imgs,
                                              u16* __restrict__ magdir) {
    int t = blockIdx.x * 256 + threadIdx.x;     // 8 pixels per thread
    int x0 = (t & 63) * 8;
    int y  = (t >> 6) & 511;
    int im = t >> 15;
    const u8* base = imgs + (size_t)im * HWSZ;
    int rows[3];
    rows[0] = (y == 0) ? 0 : y - 1;
    rows[1] = y;
    rows[2] = (y == 511) ? 511 : y + 1;
    int bb[3][10];
#pragma unroll
    for (int r = 0; r < 3; ++r) {
        const u8* rp = base + rows[r] * WW;
        u64 m = *(const u64*)(rp + x0);
        bb[r][0] = (x0 == 0) ? rp[0] : rp[x0 - 1];
#pragma unroll
        for (int i = 0; i < 8; ++i) bb[r][i + 1] = (int)((m >> (8 * i)) & 0xFF);
        bb[r][9] = (x0 == 504) ? rp[511] : rp[x0 + 8];
    }
    u32 v[8];
#pragma unroll
    for (int i = 0; i < 8; ++i) {
        int a00 = bb[0][i], a01 = bb[0][i + 1], a02 = bb[0][i + 2];
        int a10 = bb[1][i],                     a12 = bb[1][i + 2];
        int a20 = bb[2][i], a21 = bb[2][i + 1], a22 = bb[2][i + 2];
        int gx = (a02 + 2 * a12 + a22) - (a00 + 2 * a10 + a20);
        int gy = (a20 + 2 * a21 + a22) - (a00 + 2 * a01 + a02);
        int ax = gx < 0 ? -gx : gx;
        int ay = gy < 0 ? -gy : gy;
        int mag = ax + ay;
        float fax = (float)ax, fay = (float)ay;
        int dir;
        if (fay < 0.41421356237309515f * fax) dir = 0;           // <22.5 or >=157.5
        else if (fay >= 2.414213562373095f * fax) dir = 2;       // [67.5,112.5)
        else dir = ((gx ^ gy) >= 0) ? 1 : 3;                     // 45 : 135
        v[i] = (u32)mag | ((u32)dir << 12);
    }
    uint4 o;
    o.x = v[0] | (v[1] << 16);
    o.y = v[2] | (v[3] << 16);
    o.z = v[4] | (v[5] << 16);
    o.w = v[6] | (v[7] << 16);
    *(uint4*)(magdir + (size_t)im * HWSZ + y * WW + x0) = o;
}

// ---------------------------------------------------------------------------
// 4) NMS + double threshold -> bit-packed weak/strong; edges initialized to
//    strong (seed state for hysteresis).
// ---------------------------------------------------------------------------
__global__ __launch_bounds__(256) void k_nms(const u16* __restrict__ magdir,
                                             u64* __restrict__ weak,
                                             u64* __restrict__ strong,
                                             u64* __restrict__ edges) {
    int t = blockIdx.x * 256 + threadIdx.x;     // one pixel per thread
    int x  = t & 511;
    int y  = (t >> 9) & 511;
    int im = t >> 18;
    const u16* md = magdir + (size_t)im * HWSZ;
    u32 v = md[y * WW + x];
    int mag = v & 0xFFF;
    int dir = v >> 12;
    auto M = [&](int yy, int xx) -> int {
        if ((unsigned)yy > 511u || (unsigned)xx > 511u) return 0;
        return md[yy * WW + xx] & 0xFFF;
    };
    int n1, n2;
    switch (dir) {
        case 0:  n1 = M(y, x - 1);     n2 = M(y, x + 1);     break;
        case 1:  n1 = M(y - 1, x + 1); n2 = M(y + 1, x - 1); break;
        case 2:  n1 = M(y - 1, x);     n2 = M(y + 1, x);     break;
        default: n1 = M(y - 1, x - 1); n2 = M(y + 1, x + 1); break;
    }
    bool keep = (mag >= n1) && (mag >= n2);
    u64 wb = __ballot(keep && mag > 100);
    u64 sb = __ballot(keep && mag > 200);
    if ((threadIdx.x & 63) == 0) {
        size_t w = ((size_t)im * HH + y) * 8 + (x >> 6);
        weak[w] = wb;
        strong[w] = sb;
        edges[w] = sb;
    }
}

// ---------------------------------------------------------------------------
// 5a) tile-local hysteresis: one wave per 64x64 tile (lane=row, u64=64 cols),
//     barrier-free iteration to local fixed point with frozen 1-px halo from
//     global state. Monotone chaotic iteration: result is always a subset of
//     the least fixed point, superset of input. Run a few rounds.
// ---------------------------------------------------------------------------
__global__ __launch_bounds__(256) void k_hyst_tile(const u64* __restrict__ weakg,
                                                   u64* __restrict__ edges) {
    int wv = blockIdx.x * 4 + (threadIdx.x >> 6);   // tile id 0..1023
    int lane = threadIdx.x & 63;
    int im = wv >> 6;
    int ty = (wv >> 3) & 7;
    int tx = wv & 7;
    int row = ty * 64 + lane;
    size_t base = (size_t)im * (HH * 8) + (size_t)row * 8 + tx;
    u64 s  = edges[base];
    u64 wk = weakg[base];
    u64 wl = (tx > 0) ? edges[base - 1] : 0ull;   // frozen left column word
    u64 wr = (tx < 7) ? edges[base + 1] : 0ull;   // frozen right column word
    u64 lb = wl >> 63;                // contribution into bit 0
    u64 rb = (wr & 1ull) << 63;       // contribution into bit 63
    u64 up_h = 0ull, dn_h = 0ull;     // frozen dilated boundary rows
    if (lane == 0 && ty > 0) {
        u64 uw = edges[base - 8];
        u64 ul = (tx > 0) ? edges[base - 9] : 0ull;
        u64 ur = (tx < 7) ? edges[base - 7] : 0ull;
        up_h = uw | (uw << 1) | (uw >> 1) | (ul >> 63) | ((ur & 1ull) << 63);
    }
    if (lane == 63 && ty < 7) {
        u64 dw = edges[base + 8];
        u64 dl = (tx > 0) ? edges[base + 7] : 0ull;
        u64 dr = (tx < 7) ? edges[base + 9] : 0ull;
        dn_h = dw | (dw << 1) | (dw >> 1) | (dl >> 63) | ((dr & 1ull) << 63);
    }
    for (int it = 0; it < 130; ++it) {
        u64 hh = s | (s << 1) | (s >> 1) | lb | rb;
        u64 up = __shfl_up(hh, 1);
        if (lane == 0) up = up_h;
        u64 dn = __shfl_down(hh, 1);
        if (lane == 63) dn = dn_h;
        u64 t = wk & (hh | up | dn) & ~s;
        if (__ballot(t != 0ull) == 0ull) break;
        s |= t;
    }
    edges[base] = s;
}

// ---------------------------------------------------------------------------
// 5b) exact global hysteresis finish: one block per image; one row per
//     thread; Jacobi to fixed point (cap 256), seeded from tile-phase state.
//     Monotone => result == least fixed point == reference output.
// ---------------------------------------------------------------------------
__global__ __launch_bounds__(512) void k_hyst(const u64* __restrict__ weakg,
                                              const u64* __restrict__ strongg,
                                              u64* __restrict__ edges) {
    __shared__ u64 h[512][8];
    __shared__ int flags[2];
    int y = threadIdx.x;
    int im = blockIdx.x;
    size_t base = ((size_t)im * HH + y) * 8;
    u64 wk[8], st[8], s[8];
#pragma unroll
    for (int j = 0; j < 8; ++j) {
        wk[j] = weakg[base + j];
        st[j] = strongg[base + j];
        s[j] = edges[base + j];          // seed from tile phase
    }
    for (int it = 0; it < 256; ++it) {
        u64 hh[8];
#pragma unroll
        for (int j = 0; j < 8; ++j) hh[j] = s[j] | (s[j] << 1) | (s[j] >> 1);
#pragma unroll
        for (int j = 1; j < 8; ++j) hh[j] |= s[j - 1] >> 63;
#pragma unroll
        for (int j = 0; j < 7; ++j) hh[j] |= s[j + 1] << 63;
#pragma unroll
        for (int j = 0; j < 8; ++j) h[y][j] = hh[j];
        if (threadIdx.x == 0 && it == 0) flags[0] = 0;
        __syncthreads();                              // sync1
        if (threadIdx.x == 0) flags[(it + 1) & 1] = 0;
        int changed = 0;
#pragma unroll
        for (int j = 0; j < 8; ++j) {
            u64 up = (y > 0)   ? h[y - 1][j] : 0ull;
            u64 dn = (y < 511) ? h[y + 1][j] : 0ull;
            u64 ns = (wk[j] & (hh[j] | up | dn)) | st[j] | s[j];
            changed |= (ns != s[j]);
            s[j] = ns;
        }
        if (changed) flags[it & 1] = 1;
        __syncthreads();                              // sync2
        if (!flags[it & 1]) break;
    }
#pragma unroll
    for (int j = 0; j < 8; ++j) edges[base + j] = s[j];
}

// ---------------------------------------------------------------------------
// 6) loss. Per column (b,w): k = popcount(ep col), Z = 512 + (e-1)*k,
//    col = elsum*log(Z) - overlap; out = mean over 4096 columns.
// ---------------------------------------------------------------------------
__global__ void k_zero(float* out) {
    if (threadIdx.x == 0 && blockIdx.x == 0) out[0] = 0.0f;
}

__global__ __launch_bounds__(256) void k_loss(const u64* __restrict__ edges,
                                              float* __restrict__ out) {
    int b = blockIdx.x >> 3;        // image pair index
    int j = blockIdx.x & 7;         // word column
    int wave = threadIdx.x >> 6;
    int lane = threadIdx.x & 63;
    const u64* ep = edges + ((size_t)b * HH) * 8 + j;
    const u64* el = edges + ((size_t)(b + 8) * HH) * 8 + j;
    int k = 0, es = 0, ov = 0;
    int y0 = wave * 128;
    for (int y = y0; y < y0 + 128; ++y) {
        u64 wp = ep[(size_t)y * 8];
        u64 wl = el[(size_t)y * 8];
        int bp = (int)((wp >> lane) & 1ull);
        int bl = (int)((wl >> lane) & 1ull);
        k += bp; es += bl; ov += (bp & bl);
    }
    __shared__ int red[3][4][64];
    red[0][wave][lane] = k;
    red[1][wave][lane] = es;
    red[2][wave][lane] = ov;
    __syncthreads();
    if (threadIdx.x < 64) {
        int l = threadIdx.x;
        int K = red[0][0][l] + red[0][1][l] + red[0][2][l] + red[0][3][l];
        int E = red[1][0][l] + red[1][1][l] + red[1][2][l] + red[1][3][l];
        int O = red[2][0][l] + red[2][1][l] + red[2][2][l] + red[2][3][l];
        float logZ = logf(512.0f + 1.7182818284590452f * (float)K);
        float v = ((float)E * logZ - (float)O) * (1.0f / 4096.0f);
#pragma unroll
        for (int o = 32; o > 0; o >>= 1) v += __shfl_down(v, o, 64);
        if (l == 0) atomicAdd(out, v);
    }
}

// ---------------------------------------------------------------------------
extern "C" void kernel_launch(void* const* d_in, const int* in_sizes, int n_in,
                              void* d_out, int out_size, void* d_ws, size_t ws_size,
                              hipStream_t stream) {
    const float* pred = (const float*)d_in[0];
    const float* labels = (const float*)d_in[1];
    float* out = (float*)d_out;

    // workspace layout (bytes)
    u8*  imgs   = (u8*)d_ws;                                        // 16*HWSZ      = 4 MiB
    u16* magdir = (u16*)((char*)d_ws + (size_t)NIMG * HWSZ);        // 16*HWSZ*2    = 8 MiB
    u64* weak   = (u64*)((char*)d_ws + (size_t)NIMG * HWSZ * 3);    // 512 KiB
    u64* strong = (u64*)((char*)weak + (size_t)NIMG * HH * 8 * 8);  // 512 KiB
    u64* edges  = (u64*)((char*)strong + (size_t)NIMG * HH * 8 * 8);// 512 KiB

    hipLaunchKernelGGL(k_argmax, dim3(BB * HWSZ / 4 / 256), dim3(256), 0, stream,
                       pred, imgs);
    hipLaunchKernelGGL(k_imgl, dim3(BB * HWSZ / 4 / 256), dim3(256), 0, stream,
                       labels, imgs + (size_t)BB * HWSZ);
    hipLaunchKernelGGL(k_grad, dim3(NIMG * HH * 64 / 256), dim3(256), 0, stream,
                       imgs, magdir);
    hipLaunchKernelGGL(k_nms, dim3(NIMG * HWSZ / 256), dim3(256), 0, stream,
                       magdir, weak, strong, edges);
    hipLaunchKernelGGL(k_hyst_tile, dim3(256), dim3(256), 0, stream, weak, edges);
    hipLaunchKernelGGL(k_hyst_tile, dim3(256), dim3(256), 0, stream, weak, edges);
    hipLaunchKernelGGL(k_hyst_tile, dim3(256), dim3(256), 0, stream, weak, edges);
    hipLaunchKernelGGL(k_hyst, dim3(NIMG), dim3(512), 0, stream,
                       weak, strong, edges);
    hipLaunchKernelGGL(k_zero, dim3(1), dim3(64), 0, stream, out);
    hipLaunchKernelGGL(k_loss, dim3(64), dim3(256), 0, stream, edges, out);
}

// Round 3
// 270.569 us; speedup vs baseline: 1.0435x; 1.0435x over previous
//
#include <hip/hip_runtime.h>
#include <hip/hip_bf16.h>
#include <math.h>

typedef unsigned long long u64;
typedef unsigned char u8;
typedef unsigned short u16;
typedef unsigned int u32;

#define BB 8
#define CC 19
#define HH 512
#define WW 512
#define HWSZ (HH*WW)
#define NIMG 16

// ---------------------------------------------------------------------------
// 1) fused: argmax over channels -> img_p = (u8)(-cls); img_l = floor(lab*255);
//    zero the loss accumulator.
// ---------------------------------------------------------------------------
__global__ __launch_bounds__(256) void k_pre(const float* __restrict__ pred,
                                             const float* __restrict__ lab,
                                             u8* __restrict__ img,
                                             float* __restrict__ out) {
    int idx = blockIdx.x * 256 + threadIdx.x;   // 4 pixels per thread
    if (idx == 0) out[0] = 0.0f;
    int p4 = idx * 4;
    int b = p4 / HWSZ;
    int rem = p4 - b * HWSZ;
    const float4* base = (const float4*)(pred + (size_t)b * CC * HWSZ + rem);
    float4 best = base[0];
    int ix = 0, iy = 0, iz = 0, iw = 0;
    for (int c = 1; c < CC; ++c) {
        float4 v = base[(size_t)c * (HWSZ / 4)];
        if (v.x > best.x) { best.x = v.x; ix = c; }
        if (v.y > best.y) { best.y = v.y; iy = c; }
        if (v.z > best.z) { best.z = v.z; iz = c; }
        if (v.w > best.w) { best.w = v.w; iw = c; }
    }
    uchar4 o;
    o.x = (u8)(-ix); o.y = (u8)(-iy); o.z = (u8)(-iz); o.w = (u8)(-iw);
    *(uchar4*)(img + p4) = o;
    // labels image
    float4 v = *(const float4*)(lab + p4);
    uchar4 ol;
    ol.x = (u8)(v.x * 255.0f);
    ol.y = (u8)(v.y * 255.0f);
    ol.z = (u8)(v.z * 255.0f);
    ol.w = (u8)(v.w * 255.0f);
    *(uchar4*)(img + (size_t)BB * HWSZ + p4) = ol;
}

// ---------------------------------------------------------------------------
// 2) Sobel (edge-replicate pad) + L1 mag + quantized direction.
//    magdir = mag (12 bits, <=2040) | dir<<12, dir in {0:0deg,1:45,2:90,3:135}
// ---------------------------------------------------------------------------
__global__ __launch_bounds__(256) void k_grad(const u8* __restrict__ imgs,
                                              u16* __restrict__ magdir) {
    int t = blockIdx.x * 256 + threadIdx.x;     // 8 pixels per thread
    int x0 = (t & 63) * 8;
    int y  = (t >> 6) & 511;
    int im = t >> 15;
    const u8* base = imgs + (size_t)im * HWSZ;
    int rows[3];
    rows[0] = (y == 0) ? 0 : y - 1;
    rows[1] = y;
    rows[2] = (y == 511) ? 511 : y + 1;
    int bb[3][10];
#pragma unroll
    for (int r = 0; r < 3; ++r) {
        const u8* rp = base + rows[r] * WW;
        u64 m = *(const u64*)(rp + x0);
        bb[r][0] = (x0 == 0) ? rp[0] : rp[x0 - 1];
#pragma unroll
        for (int i = 0; i < 8; ++i) bb[r][i + 1] = (int)((m >> (8 * i)) & 0xFF);
        bb[r][9] = (x0 == 504) ? rp[511] : rp[x0 + 8];
    }
    u32 v[8];
#pragma unroll
    for (int i = 0; i < 8; ++i) {
        int a00 = bb[0][i], a01 = bb[0][i + 1], a02 = bb[0][i + 2];
        int a10 = bb[1][i],                     a12 = bb[1][i + 2];
        int a20 = bb[2][i], a21 = bb[2][i + 1], a22 = bb[2][i + 2];
        int gx = (a02 + 2 * a12 + a22) - (a00 + 2 * a10 + a20);
        int gy = (a20 + 2 * a21 + a22) - (a00 + 2 * a01 + a02);
        int ax = gx < 0 ? -gx : gx;
        int ay = gy < 0 ? -gy : gy;
        int mag = ax + ay;
        float fax = (float)ax, fay = (float)ay;
        int dir;
        if (fay < 0.41421356237309515f * fax) dir = 0;           // <22.5 or >=157.5
        else if (fay >= 2.414213562373095f * fax) dir = 2;       // [67.5,112.5)
        else dir = ((gx ^ gy) >= 0) ? 1 : 3;                     // 45 : 135
        v[i] = (u32)mag | ((u32)dir << 12);
    }
    uint4 o;
    o.x = v[0] | (v[1] << 16);
    o.y = v[2] | (v[3] << 16);
    o.z = v[4] | (v[5] << 16);
    o.w = v[6] | (v[7] << 16);
    *(uint4*)(magdir + (size_t)im * HWSZ + y * WW + x0) = o;
}

// ---------------------------------------------------------------------------
// 3) NMS + double threshold -> bit-packed weak/strong
// ---------------------------------------------------------------------------
__global__ __launch_bounds__(256) void k_nms(const u16* __restrict__ magdir,
                                             u64* __restrict__ weak,
                                             u64* __restrict__ strong) {
    int t = blockIdx.x * 256 + threadIdx.x;     // one pixel per thread
    int x  = t & 511;
    int y  = (t >> 9) & 511;
    int im = t >> 18;
    const u16* md = magdir + (size_t)im * HWSZ;
    u32 v = md[y * WW + x];
    int mag = v & 0xFFF;
    int dir = v >> 12;
    auto M = [&](int yy, int xx) -> int {
        if ((unsigned)yy > 511u || (unsigned)xx > 511u) return 0;
        return md[yy * WW + xx] & 0xFFF;
    };
    int n1, n2;
    switch (dir) {
        case 0:  n1 = M(y, x - 1);     n2 = M(y, x + 1);     break;
        case 1:  n1 = M(y - 1, x + 1); n2 = M(y + 1, x - 1); break;
        case 2:  n1 = M(y - 1, x);     n2 = M(y + 1, x);     break;
        default: n1 = M(y - 1, x - 1); n2 = M(y + 1, x + 1); break;
    }
    bool keep = (mag >= n1) && (mag >= n2);
    u64 wb = __ballot(keep && mag > 100);
    u64 sb = __ballot(keep && mag > 200);
    if ((threadIdx.x & 63) == 0) {
        size_t w = ((size_t)im * HH + y) * 8 + (x >> 6);
        weak[w] = wb;
        strong[w] = sb;
    }
}

// ---------------------------------------------------------------------------
// 4) hysteresis to least fixed point. One block/image, one row (8 u64)/thread.
//    Each iteration: complete horizontal run-fill of seeds through weak runs
//    (bit-carry trick, whole 512-bit row) + one vertical/diagonal Jacobi hop
//    through conflict-free split-u32 LDS. Monotone chaotic iteration, each
//    step is a superset of one reference Jacobi step => converges to the same
//    fixed point in fewer iterations than the reference (which converges
//    within its 256 cap, as proven by prior exact runs).
// ---------------------------------------------------------------------------
__global__ __launch_bounds__(512) void k_hyst(const u64* __restrict__ weakg,
                                              const u64* __restrict__ strongg,
                                              u64* __restrict__ edges) {
    __shared__ u32 hlo[8][512];   // lane stride 4B -> bank = y%32 -> conflict-free
    __shared__ u32 hhi[8][512];
    __shared__ int flags[2];
    int y = threadIdx.x;
    int im = blockIdx.x;
    size_t base = ((size_t)im * HH + y) * 8;
    u64 wk[8], s[8];
#pragma unroll
    for (int j = 0; j < 8; ++j) {
        wk[j] = weakg[base + j];
        s[j] = strongg[base + j];     // strong subset of weak
    }
    for (int it = 0; it < 256; ++it) {
        u64 diff = 0;
        // ---- horizontal fill rightward (increasing x) ----
        u64 c = 0;
#pragma unroll
        for (int j = 0; j < 8; ++j) {
            u64 a = s[j], w = wk[j];
            u64 t1 = a + w;       u64 c1 = (u64)(t1 < a);
            u64 t2 = t1 + c;      u64 c2 = (u64)(t2 < t1);
            u64 ns = a | ((t2 ^ w) & w);
            diff |= ns ^ a;
            s[j] = ns;
            c = c1 | c2;
        }
        // ---- horizontal fill leftward (decreasing x) via bit reversal ----
        c = 0;
#pragma unroll
        for (int j = 7; j >= 0; --j) {
            u64 a = __builtin_bitreverse64(s[j]);
            u64 w = __builtin_bitreverse64(wk[j]);
            u64 t1 = a + w;       u64 c1 = (u64)(t1 < a);
            u64 t2 = t1 + c;      u64 c2 = (u64)(t2 < t1);
            u64 nsr = a | ((t2 ^ w) & w);
            u64 ns = __builtin_bitreverse64(nsr);
            diff |= ns ^ s[j];
            s[j] = ns;
            c = c1 | c2;
        }
        // ---- horizontally dilated row -> LDS ----
        u64 hh[8];
#pragma unroll
        for (int j = 0; j < 8; ++j) hh[j] = s[j] | (s[j] << 1) | (s[j] >> 1);
#pragma unroll
        for (int j = 1; j < 8; ++j) hh[j] |= s[j - 1] >> 63;
#pragma unroll
        for (int j = 0; j < 7; ++j) hh[j] |= s[j + 1] << 63;
#pragma unroll
        for (int j = 0; j < 8; ++j) {
            hlo[j][y] = (u32)hh[j];
            hhi[j][y] = (u32)(hh[j] >> 32);
        }
        if (y == 0 && it == 0) flags[0] = 0;
        __syncthreads();                              // sync1
        if (y == 0) flags[(it + 1) & 1] = 0;
        // ---- vertical/diagonal hop ----
#pragma unroll
        for (int j = 0; j < 8; ++j) {
            u64 up = (y > 0)   ? ((u64)hlo[j][y - 1] | ((u64)hhi[j][y - 1] << 32)) : 0ull;
            u64 dn = (y < 511) ? ((u64)hlo[j][y + 1] | ((u64)hhi[j][y + 1] << 32)) : 0ull;
            u64 t = wk[j] & (up | dn) & ~s[j];
            diff |= t;
            s[j] |= t;
        }
        if (diff) flags[it & 1] = 1;
        __syncthreads();                              // sync2
        if (!flags[it & 1]) break;
    }
#pragma unroll
    for (int j = 0; j < 8; ++j) edges[base + j] = s[j];
}

// ---------------------------------------------------------------------------
// 5) loss. Per column (b,w): k = popcount(ep col), Z = 512 + (e-1)*k,
//    col = elsum*log(Z) - overlap; out = mean over 4096 columns.
// ---------------------------------------------------------------------------
__global__ __launch_bounds__(256) void k_loss(const u64* __restrict__ edges,
                                              float* __restrict__ out) {
    int b = blockIdx.x >> 3;        // image pair index
    int j = blockIdx.x & 7;         // word column
    int wave = threadIdx.x >> 6;
    int lane = threadIdx.x & 63;
    const u64* ep = edges + ((size_t)b * HH) * 8 + j;
    const u64* el = edges + ((size_t)(b + 8) * HH) * 8 + j;
    int k = 0, es = 0, ov = 0;
    int y0 = wave * 128;
    for (int y = y0; y < y0 + 128; ++y) {
        u64 wp = ep[(size_t)y * 8];
        u64 wl = el[(size_t)y * 8];
        int bp = (int)((wp >> lane) & 1ull);
        int bl = (int)((wl >> lane) & 1ull);
        k += bp; es += bl; ov += (bp & bl);
    }
    __shared__ int red[3][4][64];
    red[0][wave][lane] = k;
    red[1][wave][lane] = es;
    red[2][wave][lane] = ov;
    __syncthreads();
    if (threadIdx.x < 64) {
        int l = threadIdx.x;
        int K = red[0][0][l] + red[0][1][l] + red[0][2][l] + red[0][3][l];
        int E = red[1][0][l] + red[1][1][l] + red[1][2][l] + red[1][3][l];
        int O = red[2][0][l] + red[2][1][l] + red[2][2][l] + red[2][3][l];
        float logZ = logf(512.0f + 1.7182818284590452f * (float)K);
        float v = ((float)E * logZ - (float)O) * (1.0f / 4096.0f);
#pragma unroll
        for (int o = 32; o > 0; o >>= 1) v += __shfl_down(v, o, 64);
        if (l == 0) atomicAdd(out, v);
    }
}

// ---------------------------------------------------------------------------
extern "C" void kernel_launch(void* const* d_in, const int* in_sizes, int n_in,
                              void* d_out, int out_size, void* d_ws, size_t ws_size,
                              hipStream_t stream) {
    const float* pred = (const float*)d_in[0];
    const float* labels = (const float*)d_in[1];
    float* out = (float*)d_out;

    // workspace layout (bytes)
    u8*  imgs   = (u8*)d_ws;                                        // 16*HWSZ      = 4 MiB
    u16* magdir = (u16*)((char*)d_ws + (size_t)NIMG * HWSZ);        // 16*HWSZ*2    = 8 MiB
    u64* weak   = (u64*)((char*)d_ws + (size_t)NIMG * HWSZ * 3);    // 512 KiB
    u64* strong = (u64*)((char*)weak + (size_t)NIMG * HH * 8 * 8);  // 512 KiB
    u64* edges  = (u64*)((char*)strong + (size_t)NIMG * HH * 8 * 8);// 512 KiB

    hipLaunchKernelGGL(k_pre, dim3(BB * HWSZ / 4 / 256), dim3(256), 0, stream,
                       pred, labels, imgs, out);
    hipLaunchKernelGGL(k_grad, dim3(NIMG * HH * 64 / 256), dim3(256), 0, stream,
                       imgs, magdir);
    hipLaunchKernelGGL(k_nms, dim3(NIMG * HWSZ / 256), dim3(256), 0, stream,
                       magdir, weak, strong);
    hipLaunchKernelGGL(k_hyst, dim3(NIMG), dim3(512), 0, stream,
                       weak, strong, edges);
    hipLaunchKernelGGL(k_loss, dim3(64), dim3(256), 0, stream, edges, out);
}

// Round 4
// 248.125 us; speedup vs baseline: 1.1379x; 1.0905x over previous
//
#include <hip/hip_runtime.h>
#include <hip/hip_bf16.h>
#include <math.h>

typedef unsigned long long u64;
typedef unsigned char u8;
typedef unsigned short u16;
typedef unsigned int u32;

#define BB 8
#define CC 19
#define HH 512
#define WW 512
#define HWSZ (HH*WW)
#define NIMG 16

// ---------------------------------------------------------------------------
// 1) fused: argmax over channels -> img_p = (u8)(-cls); img_l = floor(lab*255);
//    zero the loss accumulator.  HBM-bound: must read all 168 MB of inputs.
// ---------------------------------------------------------------------------
__global__ __launch_bounds__(256) void k_pre(const float* __restrict__ pred,
                                             const float* __restrict__ lab,
                                             u8* __restrict__ img,
                                             float* __restrict__ out) {
    int idx = blockIdx.x * 256 + threadIdx.x;   // 4 pixels per thread
    if (idx == 0) out[0] = 0.0f;
    int p4 = idx * 4;
    int b = p4 / HWSZ;
    int rem = p4 - b * HWSZ;
    const float4* base = (const float4*)(pred + (size_t)b * CC * HWSZ + rem);
    float4 best = base[0];
    int ix = 0, iy = 0, iz = 0, iw = 0;
    for (int c = 1; c < CC; ++c) {
        float4 v = base[(size_t)c * (HWSZ / 4)];
        if (v.x > best.x) { best.x = v.x; ix = c; }
        if (v.y > best.y) { best.y = v.y; iy = c; }
        if (v.z > best.z) { best.z = v.z; iz = c; }
        if (v.w > best.w) { best.w = v.w; iw = c; }
    }
    uchar4 o;
    o.x = (u8)(-ix); o.y = (u8)(-iy); o.z = (u8)(-iz); o.w = (u8)(-iw);
    *(uchar4*)(img + p4) = o;
    float4 v = *(const float4*)(lab + p4);
    uchar4 ol;
    ol.x = (u8)(v.x * 255.0f);
    ol.y = (u8)(v.y * 255.0f);
    ol.z = (u8)(v.z * 255.0f);
    ol.w = (u8)(v.w * 255.0f);
    *(uchar4*)(img + (size_t)BB * HWSZ + p4) = ol;
}

// ---------------------------------------------------------------------------
// Sobel for 8 pixels of one row (edge-replicate padding). mag <= 2040.
// ---------------------------------------------------------------------------
__device__ __forceinline__ void sobel8(const u8* __restrict__ base, int yy, int x0,
                                       int mag8[8], u32* dirpack) {
    int r0 = (yy == 0) ? 0 : yy - 1;
    int r2 = (yy == 511) ? 511 : yy + 1;
    const u8* rps[3] = { base + r0 * WW, base + yy * WW, base + r2 * WW };
    int bb[3][10];
#pragma unroll
    for (int r = 0; r < 3; ++r) {
        u64 m = *(const u64*)(rps[r] + x0);
        bb[r][0] = (x0 == 0) ? rps[r][0] : rps[r][x0 - 1];
#pragma unroll
        for (int i = 0; i < 8; ++i) bb[r][i + 1] = (int)((m >> (8 * i)) & 0xFF);
        bb[r][9] = (x0 == 504) ? rps[r][511] : rps[r][x0 + 8];
    }
    u32 dp = 0;
#pragma unroll
    for (int i = 0; i < 8; ++i) {
        int a00 = bb[0][i], a01 = bb[0][i + 1], a02 = bb[0][i + 2];
        int a10 = bb[1][i],                     a12 = bb[1][i + 2];
        int a20 = bb[2][i], a21 = bb[2][i + 1], a22 = bb[2][i + 2];
        int gx = (a02 + 2 * a12 + a22) - (a00 + 2 * a10 + a20);
        int gy = (a20 + 2 * a21 + a22) - (a00 + 2 * a01 + a02);
        int ax = gx < 0 ? -gx : gx;
        int ay = gy < 0 ? -gy : gy;
        mag8[i] = ax + ay;
        if (dirpack) {
            float fax = (float)ax, fay = (float)ay;
            u32 dir;
            if (fay < 0.41421356237309515f * fax) dir = 0;       // <22.5 or >=157.5
            else if (fay >= 2.414213562373095f * fax) dir = 2;   // [67.5,112.5)
            else dir = ((gx ^ gy) >= 0) ? 1u : 3u;               // 45 : 135
            dp |= dir << (2 * i);
        }
    }
    if (dirpack) *dirpack = dp;
}

// ---------------------------------------------------------------------------
// 2) fused Sobel + NMS + double threshold -> bit-packed weak/strong.
//    Block = 4-row x 512-col strip; 6 mag rows staged in LDS (zeroed edge
//    cols emulate the reference's zero-pad of mag). 1.5x Sobel redundancy
//    replaces the 8 MB magdir global round-trip.
// ---------------------------------------------------------------------------
__global__ __launch_bounds__(256) void k_gradnms(const u8* __restrict__ imgs,
                                                 u64* __restrict__ weak,
                                                 u64* __restrict__ strong) {
    __shared__ u16 smag[6][514];         // [row y0-1 .. y0+4][1 + x], cols 0,513 = 0
    __shared__ alignas(8) u8 wb[4][64];
    __shared__ alignas(8) u8 sb[4][64];
    int im = blockIdx.x >> 7;            // 128 strips per image
    int y0 = (blockIdx.x & 127) * 4;
    int r    = threadIdx.x >> 6;         // wave index = row in strip (uniform branches)
    int lane = threadIdx.x & 63;
    int x0 = lane * 8;
    const u8* base = imgs + (size_t)im * HWSZ;

    if (threadIdx.x < 6) { smag[threadIdx.x][0] = 0; smag[threadIdx.x][513] = 0; }

    // pass A: own row mag + dir
    int y = y0 + r;
    int mag8[8]; u32 dp;
    sobel8(base, y, x0, mag8, &dp);
#pragma unroll
    for (int i = 0; i < 8; ++i) smag[r + 1][1 + x0 + i] = (u16)mag8[i];

    // pass B: halo rows (wave-uniform divergence)
    if (r == 0) {
        if (y0 > 0) {
            int m2[8]; sobel8(base, y0 - 1, x0, m2, nullptr);
#pragma unroll
            for (int i = 0; i < 8; ++i) smag[0][1 + x0 + i] = (u16)m2[i];
        } else {
#pragma unroll
            for (int i = 0; i < 8; ++i) smag[0][1 + x0 + i] = 0;
        }
    } else if (r == 3) {
        if (y0 + 4 < 512) {
            int m2[8]; sobel8(base, y0 + 4, x0, m2, nullptr);
#pragma unroll
            for (int i = 0; i < 8; ++i) smag[5][1 + x0 + i] = (u16)m2[i];
        } else {
#pragma unroll
            for (int i = 0; i < 8; ++i) smag[5][1 + x0 + i] = 0;
        }
    }
    __syncthreads();

    // NMS + thresholds
    int wbits = 0, sbits = 0;
#pragma unroll
    for (int i = 0; i < 8; ++i) {
        int x = x0 + i;
        int mag = mag8[i];
        int dir = (int)((dp >> (2 * i)) & 3u);
        int n1, n2;
        switch (dir) {
            case 0:  n1 = smag[r + 1][x];     n2 = smag[r + 1][x + 2]; break;
            case 1:  n1 = smag[r][x + 2];     n2 = smag[r + 2][x];     break;
            case 2:  n1 = smag[r][x + 1];     n2 = smag[r + 2][x + 1]; break;
            default: n1 = smag[r][x];         n2 = smag[r + 2][x + 2]; break;
        }
        int keep = (mag >= n1) & (mag >= n2);
        wbits |= (keep & (mag > 100)) << i;
        sbits |= (keep & (mag > 200)) << i;
    }
    wb[r][lane] = (u8)wbits;
    sb[r][lane] = (u8)sbits;
    __syncthreads();

    if (threadIdx.x < 32) {
        int rr = threadIdx.x >> 3;       // row in strip
        int w  = threadIdx.x & 7;        // u64 word in row
        u64 W = *(const u64*)&wb[rr][w * 8];   // little-endian byte k -> bits 8k
        u64 S = *(const u64*)&sb[rr][w * 8];
        size_t o = ((size_t)im * HH + (y0 + rr)) * 8 + w;
        weak[o] = W;
        strong[o] = S;
    }
}

// ---------------------------------------------------------------------------
// 3) hysteresis to least fixed point. One block/image, one row (8 u64)/thread.
//    Horizontal run-fill (bit-carry) + vertical Jacobi hop through
//    conflict-free split-u32 LDS. Monotone chaotic iteration => same fixed
//    point as the reference's (converged) 256-cap Jacobi.
// ---------------------------------------------------------------------------
__global__ __launch_bounds__(512) void k_hyst(const u64* __restrict__ weakg,
                                              const u64* __restrict__ strongg,
                                              u64* __restrict__ edges) {
    __shared__ u32 hlo[8][512];   // lane stride 4B -> bank = y%32 -> conflict-free
    __shared__ u32 hhi[8][512];
    __shared__ int flags[2];
    int y = threadIdx.x;
    int im = blockIdx.x;
    size_t base = ((size_t)im * HH + y) * 8;
    u64 wk[8], s[8];
#pragma unroll
    for (int j = 0; j < 8; ++j) {
        wk[j] = weakg[base + j];
        s[j] = strongg[base + j];     // strong subset of weak
    }
    for (int it = 0; it < 256; ++it) {
        u64 diff = 0;
        // horizontal fill rightward
        u64 c = 0;
#pragma unroll
        for (int j = 0; j < 8; ++j) {
            u64 a = s[j], w = wk[j];
            u64 t1 = a + w;       u64 c1 = (u64)(t1 < a);
            u64 t2 = t1 + c;      u64 c2 = (u64)(t2 < t1);
            u64 ns = a | ((t2 ^ w) & w);
            diff |= ns ^ a;
            s[j] = ns;
            c = c1 | c2;
        }
        // horizontal fill leftward via bit reversal
        c = 0;
#pragma unroll
        for (int j = 7; j >= 0; --j) {
            u64 a = __builtin_bitreverse64(s[j]);
            u64 w = __builtin_bitreverse64(wk[j]);
            u64 t1 = a + w;       u64 c1 = (u64)(t1 < a);
            u64 t2 = t1 + c;      u64 c2 = (u64)(t2 < t1);
            u64 nsr = a | ((t2 ^ w) & w);
            u64 ns = __builtin_bitreverse64(nsr);
            diff |= ns ^ s[j];
            s[j] = ns;
            c = c1 | c2;
        }
        // horizontally dilated row -> LDS
        u64 hh[8];
#pragma unroll
        for (int j = 0; j < 8; ++j) hh[j] = s[j] | (s[j] << 1) | (s[j] >> 1);
#pragma unroll
        for (int j = 1; j < 8; ++j) hh[j] |= s[j - 1] >> 63;
#pragma unroll
        for (int j = 0; j < 7; ++j) hh[j] |= s[j + 1] << 63;
#pragma unroll
        for (int j = 0; j < 8; ++j) {
            hlo[j][y] = (u32)hh[j];
            hhi[j][y] = (u32)(hh[j] >> 32);
        }
        if (y == 0 && it == 0) flags[0] = 0;
        __syncthreads();
        if (y == 0) flags[(it + 1) & 1] = 0;
        // vertical/diagonal hop
#pragma unroll
        for (int j = 0; j < 8; ++j) {
            u64 up = (y > 0)   ? ((u64)hlo[j][y - 1] | ((u64)hhi[j][y - 1] << 32)) : 0ull;
            u64 dn = (y < 511) ? ((u64)hlo[j][y + 1] | ((u64)hhi[j][y + 1] << 32)) : 0ull;
            u64 t = wk[j] & (up | dn) & ~s[j];
            diff |= t;
            s[j] |= t;
        }
        if (diff) flags[it & 1] = 1;
        __syncthreads();
        if (!flags[it & 1]) break;
    }
#pragma unroll
    for (int j = 0; j < 8; ++j) edges[base + j] = s[j];
}

// ---------------------------------------------------------------------------
// 4) loss. Per column (b,w): k = popcount(ep col), Z = 512 + (e-1)*k,
//    col = elsum*log(Z) - overlap; out = mean over 4096 columns.
// ---------------------------------------------------------------------------
__global__ __launch_bounds__(256) void k_loss(const u64* __restrict__ edges,
                                              float* __restrict__ out) {
    int b = blockIdx.x >> 3;        // image pair index
    int j = blockIdx.x & 7;         // word column
    int wave = threadIdx.x >> 6;
    int lane = threadIdx.x & 63;
    const u64* ep = edges + ((size_t)b * HH) * 8 + j;
    const u64* el = edges + ((size_t)(b + 8) * HH) * 8 + j;
    int k = 0, es = 0, ov = 0;
    int y0 = wave * 128;
    for (int y = y0; y < y0 + 128; ++y) {
        u64 wp = ep[(size_t)y * 8];
        u64 wl = el[(size_t)y * 8];
        int bp = (int)((wp >> lane) & 1ull);
        int bl = (int)((wl >> lane) & 1ull);
        k += bp; es += bl; ov += (bp & bl);
    }
    __shared__ int red[3][4][64];
    red[0][wave][lane] = k;
    red[1][wave][lane] = es;
    red[2][wave][lane] = ov;
    __syncthreads();
    if (threadIdx.x < 64) {
        int l = threadIdx.x;
        int K = red[0][0][l] + red[0][1][l] + red[0][2][l] + red[0][3][l];
        int E = red[1][0][l] + red[1][1][l] + red[1][2][l] + red[1][3][l];
        int O = red[2][0][l] + red[2][1][l] + red[2][2][l] + red[2][3][l];
        float logZ = logf(512.0f + 1.7182818284590452f * (float)K);
        float v = ((float)E * logZ - (float)O) * (1.0f / 4096.0f);
#pragma unroll
        for (int o = 32; o > 0; o >>= 1) v += __shfl_down(v, o, 64);
        if (l == 0) atomicAdd(out, v);
    }
}

// ---------------------------------------------------------------------------
extern "C" void kernel_launch(void* const* d_in, const int* in_sizes, int n_in,
                              void* d_out, int out_size, void* d_ws, size_t ws_size,
                              hipStream_t stream) {
    const float* pred = (const float*)d_in[0];
    const float* labels = (const float*)d_in[1];
    float* out = (float*)d_out;

    // workspace layout (bytes)
    u8*  imgs   = (u8*)d_ws;                                        // 16*HWSZ = 4 MiB
    u64* weak   = (u64*)((char*)d_ws + (size_t)NIMG * HWSZ);        // 512 KiB
    u64* strong = (u64*)((char*)weak + (size_t)NIMG * HH * 8 * 8);  // 512 KiB
    u64* edges  = (u64*)((char*)strong + (size_t)NIMG * HH * 8 * 8);// 512 KiB

    hipLaunchKernelGGL(k_pre, dim3(BB * HWSZ / 4 / 256), dim3(256), 0, stream,
                       pred, labels, imgs, out);
    hipLaunchKernelGGL(k_gradnms, dim3(NIMG * 128), dim3(256), 0, stream,
                       imgs, weak, strong);
    hipLaunchKernelGGL(k_hyst, dim3(NIMG), dim3(512), 0, stream,
                       weak, strong, edges);
    hipLaunchKernelGGL(k_loss, dim3(64), dim3(256), 0, stream, edges, out);
}